// Round 1
// 210.964 us; speedup vs baseline: 1.0232x; 1.0232x over previous
//
#include <hip/hip_runtime.h>

// GCN: 2x GCNConv(sym-norm, self-loops) + relu, then linear head.
// hsb1[i] = bf16(x@W1)[i] RAW (no dinv) [N,64]; dinv[src] folded into the
// per-edge gather weight in agg1 (m = e<end ? dinv[s] : 0) -> GEMM1 no
// longer depends on the CSR build, so scatter and GEMM1 are FUSED into one
// kernel (block-range split) and overlap on the device.
// Buckets shrunk 512->256 nodes (NBUCK 391) so both CSR kernels get ~2x
// block parallelism (391 blocks vs 196 on 256 CUs).
// Aggregation: 4 nodes/wave (16 lanes/node), 8 edges/round (4 gathers/lane
// in flight) for memory-level parallelism on the latency-bound gathers.

#define FIN 128
#define HIDDEN 64
#define NBUCK 391          // ceil(100000/256) buckets of 256 nodes
#define CAP 4608           // slots/bucket; mean 4096, sigma~64 (8 sigma headroom)
#define EPB 4096           // edges per scatter block

typedef __attribute__((ext_vector_type(8))) short bf16x8;
typedef __attribute__((ext_vector_type(4))) float f32x4;

__device__ __forceinline__ unsigned f2bf_pair(float a, float b) {
    unsigned ua = __float_as_uint(a);
    unsigned ub = __float_as_uint(b);
    ua = (ua + 0x7FFFu + ((ua >> 16) & 1u)) >> 16;
    ub = (ub + 0x7FFFu + ((ub >> 16) & 1u)) & 0xFFFF0000u;
    return ua | ub;
}
__device__ __forceinline__ unsigned short f2bf1(float a) {
    unsigned u = __float_as_uint(a);
    return (unsigned short)((u + 0x7FFFu + ((u >> 16) & 1u)) >> 16);
}
#define BF_LO(u) __uint_as_float((u) << 16)
#define BF_HI(u) __uint_as_float((u) & 0xFFFF0000u)

// ---- fused: edge scatter (blocks < nsc) + GEMM1 (blocks >= nsc) ----
// scatter: packed (src<<8|loc) into fixed bucket regions, no prescan.
// GEMM1: hsb[node][ch] = bf16( sum_k x[node][k] W1[k][ch] )  (raw, no dinv)
__global__ __launch_bounds__(256) void k_scatter_mfma1(const int* __restrict__ src,
                                                       const int* __restrict__ dst,
                                                       int* __restrict__ bcursor,
                                                       int* __restrict__ pairs, int e,
                                                       const float4* __restrict__ x4,
                                                       const float* __restrict__ w1,
                                                       uint2* __restrict__ hsb,
                                                       int n, int nsc) {
    __shared__ int sbuf[4352];            // 17408 B: sW (GEMM) / h,base,cur (scatter)
    int tid = threadIdx.x;
    if ((int)blockIdx.x < nsc) {
        int* h      = sbuf;
        int* base_s = sbuf + NBUCK;
        int* cur    = sbuf + 2 * NBUCK;
        int dloc[EPB / 256];
        for (int i = tid; i < NBUCK; i += 256) { h[i] = 0; cur[i] = 0; }
        __syncthreads();
        int start = blockIdx.x * EPB;
#pragma unroll
        for (int i = 0; i < EPB / 256; i++) {
            int idx = start + tid + i * 256;
            int d = (idx < e) ? dst[idx] : -1;
            dloc[i] = d;
            if (d >= 0) atomicAdd(&h[d >> 8], 1);
        }
        __syncthreads();
        for (int i = tid; i < NBUCK; i += 256)
            if (h[i] > 0) base_s[i] = atomicAdd(&bcursor[i], h[i]);
        __syncthreads();
#pragma unroll
        for (int i = 0; i < EPB / 256; i++) {
            int idx = start + tid + i * 256;
            int d = dloc[i];
            if (d >= 0) {
                int b = d >> 8;
                int pos = base_s[b] + atomicAdd(&cur[b], 1);
                if (pos < CAP) pairs[b * CAP + pos] = (src[idx] << 8) | (d & 255);
            }
        }
        return;
    }
    // ---- GEMM1 path ----
    unsigned short* sW = (unsigned short*)sbuf;   // W1t bf16 [ch][k], stride 136
#pragma unroll
    for (int i = 0; i < 32; i++) {
        int idx = tid + i * 256;              // 0..8191
        int k = idx >> 6, ch = idx & 63;
        sW[ch * 136 + k] = f2bf1(w1[idx]);
    }
    __syncthreads();
    int lane = tid & 63, wave = tid >> 6;
    int quad = lane >> 4, nl = lane & 15;
    int node = (blockIdx.x - nsc) * 64 + wave * 16 + nl;
    int ic = min(node, n - 1);
    const float4* px = x4 + (size_t)ic * 32 + quad * 2;
    bf16x8 bfr[4];
#pragma unroll
    for (int kc = 0; kc < 4; kc++) {
        float4 p = px[kc * 8];
        float4 q = px[kc * 8 + 1];
        union { unsigned u[4]; bf16x8 v; } t;
        t.u[0] = f2bf_pair(p.x, p.y); t.u[1] = f2bf_pair(p.z, p.w);
        t.u[2] = f2bf_pair(q.x, q.y); t.u[3] = f2bf_pair(q.z, q.w);
        bfr[kc] = t.v;
    }
    const bf16x8* sW8 = (const bf16x8*)sW;
    f32x4 a0 = {0.f, 0.f, 0.f, 0.f}, a1 = a0, a2 = a0, a3 = a0;
#pragma unroll
    for (int kc = 0; kc < 4; kc++) {
        int ko = kc * 4 + quad;
        bf16x8 w0 = sW8[(nl +  0) * 17 + ko];
        bf16x8 w1f = sW8[(nl + 16) * 17 + ko];
        bf16x8 w2f = sW8[(nl + 32) * 17 + ko];
        bf16x8 w3f = sW8[(nl + 48) * 17 + ko];
        a0 = __builtin_amdgcn_mfma_f32_16x16x32_bf16(w0,  bfr[kc], a0, 0, 0, 0);
        a1 = __builtin_amdgcn_mfma_f32_16x16x32_bf16(w1f, bfr[kc], a1, 0, 0, 0);
        a2 = __builtin_amdgcn_mfma_f32_16x16x32_bf16(w2f, bfr[kc], a2, 0, 0, 0);
        a3 = __builtin_amdgcn_mfma_f32_16x16x32_bf16(w3f, bfr[kc], a3, 0, 0, 0);
    }
    if (node < n) {
        uint2* o = hsb + (size_t)node * 16 + quad;
        o[0]  = make_uint2(f2bf_pair(a0.x, a0.y), f2bf_pair(a0.z, a0.w));
        o[4]  = make_uint2(f2bf_pair(a1.x, a1.y), f2bf_pair(a1.z, a1.w));
        o[8]  = make_uint2(f2bf_pair(a2.x, a2.y), f2bf_pair(a2.z, a2.w));
        o[12] = make_uint2(f2bf_pair(a3.x, a3.y), f2bf_pair(a3.z, a3.w));
    }
}

// ---- per-bucket exact CSR + rowinfo{start,deg} + dinv (256 nodes/bucket) ----
__global__ __launch_bounds__(256) void k_csr_bucket(const int* __restrict__ pairs,
                                                    const int* __restrict__ bcursor,
                                                    int2* __restrict__ rowinfo,
                                                    float* __restrict__ dinv,
                                                    int* __restrict__ csr_src, int n) {
    __shared__ int cnt[256];
    __shared__ int off[256];
    __shared__ int ws[256];
    int tid = threadIdx.x;
    int b = blockIdx.x;
    int node0 = b << 8;
    cnt[tid] = 0;
    __syncthreads();
    int s0 = b * CAP;
    int s1 = s0 + min(bcursor[b], CAP);
    for (int i = s0 + tid; i < s1; i += 256) atomicAdd(&cnt[pairs[i] & 255], 1);
    __syncthreads();
    int c = cnt[tid];
    ws[tid] = c;
    __syncthreads();
    for (int o = 1; o < 256; o <<= 1) {
        int x = 0;
        if (tid >= o) x = ws[tid - o];
        __syncthreads();
        ws[tid] += x;
        __syncthreads();
    }
    int excl = ws[tid] - c;
    off[tid] = excl;
    int node = node0 + tid;
    if (node < n) {
        rowinfo[node] = make_int2(s0 + excl, c);
        dinv[node] = rsqrtf((float)c + 1.0f);
    }
    cnt[tid] = 0;
    __syncthreads();
    for (int i = s0 + tid; i < s1; i += 256) {
        int p = pairs[i];
        int l = p & 255;
        int pos = s0 + off[l] + atomicAdd(&cnt[l], 1);
        csr_src[pos] = p >> 8;
    }
}

// agg layer1 + finalize + W2 GEMM fused. Block = 16 nodes (one MFMA tile).
// Phase A: gather 8 edges/round (4 gathers/lane in flight), weight
//          m = (e<end) ? dinv[src] : 0  (hsb1 is raw h).
// Phase B: 4 waves x (16ch x 16node) MFMA tiles of v @ W2 -> hsb2 (bf16,
//          dinv[dst] folded as before).
__global__ __launch_bounds__(256) void k_agg1_gemm2(const int2* __restrict__ rowinfo,
                                                    const int* __restrict__ csr_src,
                                                    const uint4* __restrict__ hsb4,
                                                    const float* __restrict__ dinv,
                                                    const float4* __restrict__ b1_4,
                                                    const float* __restrict__ w2,   // [64*64]
                                                    uint2* __restrict__ hsb2, int n) {
    __shared__ unsigned short sW[64 * 72];    // W2t bf16 [ch][k], stride 72
    __shared__ float sV[16 * 68];             // v fp32 [node][k], stride 68
    int tid = threadIdx.x;
#pragma unroll
    for (int i = 0; i < 16; i++) {
        int idx = tid + i * 256;              // 0..4095
        int k = idx >> 6, ch = idx & 63;
        sW[ch * 72 + k] = f2bf1(w2[idx]);
    }
    int lane = tid & 63;
    int node0 = blockIdx.x * 16;
    int nloc = tid >> 4;                      // 0..15
    int node = node0 + nloc;
    int el = (lane >> 3) & 1, cq = lane & 7;
    if (node < n) {
        int2 rpd = rowinfo[node];
        int start = rpd.x, deg = rpd.y;
        int end = start + deg;
        float4 accA = make_float4(0.f, 0.f, 0.f, 0.f), accB = accA;
        int nr = (deg + 7) >> 3;
        for (int r = 0; r < nr; r++) {
            int base = start + (r << 3) + el;
            int e0 = base, e1 = base + 2, e2 = base + 4, e3 = base + 6;
            int s0 = csr_src[min(e0, end - 1)];
            int s1 = csr_src[min(e1, end - 1)];
            int s2 = csr_src[min(e2, end - 1)];
            int s3 = csr_src[min(e3, end - 1)];
            float m0 = (e0 < end) ? dinv[s0] : 0.f;
            float m1 = (e1 < end) ? dinv[s1] : 0.f;
            float m2 = (e2 < end) ? dinv[s2] : 0.f;
            float m3 = (e3 < end) ? dinv[s3] : 0.f;
            uint4 g0 = hsb4[(size_t)s0 * 8 + cq];
            uint4 g1 = hsb4[(size_t)s1 * 8 + cq];
            uint4 g2 = hsb4[(size_t)s2 * 8 + cq];
            uint4 g3 = hsb4[(size_t)s3 * 8 + cq];
            accA.x += m0 * BF_LO(g0.x) + m1 * BF_LO(g1.x) + m2 * BF_LO(g2.x) + m3 * BF_LO(g3.x);
            accA.y += m0 * BF_HI(g0.x) + m1 * BF_HI(g1.x) + m2 * BF_HI(g2.x) + m3 * BF_HI(g3.x);
            accA.z += m0 * BF_LO(g0.y) + m1 * BF_LO(g1.y) + m2 * BF_LO(g2.y) + m3 * BF_LO(g3.y);
            accA.w += m0 * BF_HI(g0.y) + m1 * BF_HI(g1.y) + m2 * BF_HI(g2.y) + m3 * BF_HI(g3.y);
            accB.x += m0 * BF_LO(g0.z) + m1 * BF_LO(g1.z) + m2 * BF_LO(g2.z) + m3 * BF_LO(g3.z);
            accB.y += m0 * BF_HI(g0.z) + m1 * BF_HI(g1.z) + m2 * BF_HI(g2.z) + m3 * BF_HI(g3.z);
            accB.z += m0 * BF_LO(g0.w) + m1 * BF_LO(g1.w) + m2 * BF_LO(g2.w) + m3 * BF_LO(g3.w);
            accB.w += m0 * BF_HI(g0.w) + m1 * BF_HI(g1.w) + m2 * BF_HI(g2.w) + m3 * BF_HI(g3.w);
        }
        accA.x += __shfl_xor(accA.x, 8); accA.y += __shfl_xor(accA.y, 8);
        accA.z += __shfl_xor(accA.z, 8); accA.w += __shfl_xor(accA.w, 8);
        accB.x += __shfl_xor(accB.x, 8); accB.y += __shfl_xor(accB.y, 8);
        accB.z += __shfl_xor(accB.z, 8); accB.w += __shfl_xor(accB.w, 8);
        if (el == 0) {
            uint4 g = hsb4[(size_t)node * 8 + cq];
            float s = dinv[node];
            float sq = s * s;                 // self term: dinv^2 * h_self
            float4 bA = b1_4[cq * 2], bB = b1_4[cq * 2 + 1];
            float4 vA, vB;
            vA.x = fmaxf(s * accA.x + sq * BF_LO(g.x) + bA.x, 0.f);
            vA.y = fmaxf(s * accA.y + sq * BF_HI(g.x) + bA.y, 0.f);
            vA.z = fmaxf(s * accA.z + sq * BF_LO(g.y) + bA.z, 0.f);
            vA.w = fmaxf(s * accA.w + sq * BF_HI(g.y) + bA.w, 0.f);
            vB.x = fmaxf(s * accB.x + sq * BF_LO(g.z) + bB.x, 0.f);
            vB.y = fmaxf(s * accB.y + sq * BF_HI(g.z) + bB.y, 0.f);
            vB.z = fmaxf(s * accB.z + sq * BF_LO(g.w) + bB.z, 0.f);
            vB.w = fmaxf(s * accB.w + sq * BF_HI(g.w) + bB.w, 0.f);
            float* vb = sV + nloc * 68 + cq * 8;
            *(float4*)vb = vA;
            *(float4*)(vb + 4) = vB;
        }
    }
    __syncthreads();
    // Phase B: wave w -> output channels [w*16, w*16+16) for the 16 nodes.
    int wave = tid >> 6;
    int quad = lane >> 4, nl = lane & 15;
    const bf16x8* sW8 = (const bf16x8*)sW;
    f32x4 acc = {0.f, 0.f, 0.f, 0.f};
#pragma unroll
    for (int kc = 0; kc < 2; kc++) {
        const float* vb = sV + nl * 68 + kc * 32 + quad * 8;
        float4 p = *(const float4*)vb;
        float4 q = *(const float4*)(vb + 4);
        union { unsigned u[4]; bf16x8 v; } t;
        t.u[0] = f2bf_pair(p.x, p.y); t.u[1] = f2bf_pair(p.z, p.w);
        t.u[2] = f2bf_pair(q.x, q.y); t.u[3] = f2bf_pair(q.z, q.w);
        bf16x8 a = sW8[(wave * 16 + nl) * 9 + kc * 4 + quad];
        acc = __builtin_amdgcn_mfma_f32_16x16x32_bf16(a, t.v, acc, 0, 0, 0);
    }
    int onode = node0 + nl;
    if (onode < n) {
        float s = dinv[onode];
        hsb2[(size_t)onode * 16 + wave * 4 + quad] =
            make_uint2(f2bf_pair(acc.x * s, acc.y * s), f2bf_pair(acc.z * s, acc.w * s));
    }
}

// agg layer2 + head fused: 4 nodes/wave, 8 edges/round;
// epilogue relu(dinv*(acc+self)+b2).wc+bc   (hsb2 has dinv folded -> m in {0,1})
__global__ __launch_bounds__(256) void k_agg2_head(const int2* __restrict__ rowinfo,
                                                   const int* __restrict__ csr_src,
                                                   const uint4* __restrict__ hsb4,
                                                   const float* __restrict__ dinv,
                                                   const float4* __restrict__ b2_4,
                                                   const float4* __restrict__ wc_4,
                                                   const float* __restrict__ bc,
                                                   float* __restrict__ out, int n) {
    int lane = threadIdx.x & 63;
    int node = (blockIdx.x * 256 + threadIdx.x) >> 4;
    if (node >= n) return;
    int el = (lane >> 3) & 1, cq = lane & 7;
    int2 rpd = rowinfo[node];
    int start = rpd.x, deg = rpd.y;
    int end = start + deg;
    float4 accA = make_float4(0.f, 0.f, 0.f, 0.f), accB = accA;
    int nr = (deg + 7) >> 3;
    for (int r = 0; r < nr; r++) {
        int base = start + (r << 3) + el;
        int e0 = base, e1 = base + 2, e2 = base + 4, e3 = base + 6;
        int s0 = csr_src[min(e0, end - 1)];
        int s1 = csr_src[min(e1, end - 1)];
        int s2 = csr_src[min(e2, end - 1)];
        int s3 = csr_src[min(e3, end - 1)];
        float m0 = (e0 < end) ? 1.f : 0.f;
        float m1 = (e1 < end) ? 1.f : 0.f;
        float m2 = (e2 < end) ? 1.f : 0.f;
        float m3 = (e3 < end) ? 1.f : 0.f;
        uint4 g0 = hsb4[(size_t)s0 * 8 + cq];
        uint4 g1 = hsb4[(size_t)s1 * 8 + cq];
        uint4 g2 = hsb4[(size_t)s2 * 8 + cq];
        uint4 g3 = hsb4[(size_t)s3 * 8 + cq];
        accA.x += m0 * BF_LO(g0.x) + m1 * BF_LO(g1.x) + m2 * BF_LO(g2.x) + m3 * BF_LO(g3.x);
        accA.y += m0 * BF_HI(g0.x) + m1 * BF_HI(g1.x) + m2 * BF_HI(g2.x) + m3 * BF_HI(g3.x);
        accA.z += m0 * BF_LO(g0.y) + m1 * BF_LO(g1.y) + m2 * BF_LO(g2.y) + m3 * BF_LO(g3.y);
        accA.w += m0 * BF_HI(g0.y) + m1 * BF_HI(g1.y) + m2 * BF_HI(g2.y) + m3 * BF_HI(g3.y);
        accB.x += m0 * BF_LO(g0.z) + m1 * BF_LO(g1.z) + m2 * BF_LO(g2.z) + m3 * BF_LO(g3.z);
        accB.y += m0 * BF_HI(g0.z) + m1 * BF_HI(g1.z) + m2 * BF_HI(g2.z) + m3 * BF_HI(g3.z);
        accB.z += m0 * BF_LO(g0.w) + m1 * BF_LO(g1.w) + m2 * BF_LO(g2.w) + m3 * BF_LO(g3.w);
        accB.w += m0 * BF_HI(g0.w) + m1 * BF_HI(g1.w) + m2 * BF_HI(g2.w) + m3 * BF_HI(g3.w);
    }
    accA.x += __shfl_xor(accA.x, 8); accA.y += __shfl_xor(accA.y, 8);
    accA.z += __shfl_xor(accA.z, 8); accA.w += __shfl_xor(accA.w, 8);
    accB.x += __shfl_xor(accB.x, 8); accB.y += __shfl_xor(accB.y, 8);
    accB.z += __shfl_xor(accB.z, 8); accB.w += __shfl_xor(accB.w, 8);
    uint4 g = hsb4[(size_t)node * 8 + cq];
    float s = dinv[node];
    float4 bA = b2_4[cq * 2], bB = b2_4[cq * 2 + 1];
    float4 wA = wc_4[cq * 2], wB = wc_4[cq * 2 + 1];
    float t = fmaxf(s * (accA.x + BF_LO(g.x)) + bA.x, 0.f) * wA.x
            + fmaxf(s * (accA.y + BF_HI(g.x)) + bA.y, 0.f) * wA.y
            + fmaxf(s * (accA.z + BF_LO(g.y)) + bA.z, 0.f) * wA.z
            + fmaxf(s * (accA.w + BF_HI(g.y)) + bA.w, 0.f) * wA.w
            + fmaxf(s * (accB.x + BF_LO(g.z)) + bB.x, 0.f) * wB.x
            + fmaxf(s * (accB.y + BF_HI(g.z)) + bB.y, 0.f) * wB.y
            + fmaxf(s * (accB.z + BF_LO(g.w)) + bB.z, 0.f) * wB.z
            + fmaxf(s * (accB.w + BF_HI(g.w)) + bB.w, 0.f) * wB.w;
    t += __shfl_xor(t, 1);
    t += __shfl_xor(t, 2);
    t += __shfl_xor(t, 4);
    if ((lane & 15) == 0) out[node] = t + bc[0];
}

extern "C" void kernel_launch(void* const* d_in, const int* in_sizes, int n_in,
                              void* d_out, int out_size, void* d_ws, size_t ws_size,
                              hipStream_t stream) {
    const float* x  = (const float*)d_in[0];
    const int*   ei = (const int*)d_in[1];
    const float* W1 = (const float*)d_in[2];
    const float* b1 = (const float*)d_in[3];
    const float* W2 = (const float*)d_in[4];
    const float* b2 = (const float*)d_in[5];
    const float* Wc = (const float*)d_in[6];
    const float* bc = (const float*)d_in[7];
    int n = in_sizes[0] / FIN;      // 100000
    int e = in_sizes[1] / 2;        // 1600000
    const int* srcv = ei;
    const int* dstv = ei + e;

    char* ws = (char*)d_ws;
    float* dinv    = (float*)(ws + 0);                       // 400 KB
    int2*  rowinfo = (int2*)(ws + (512u << 10));             // 800 KB
    int*   csr_src = (int*)(ws + 1536u * 1024);              // 7.04 MB (391*4608*4)
    int*   bcursor = (int*)(ws + 8800u * 1024);              // 1564 B
    uint2* hsb1    = (uint2*)(ws + (9u << 20));              // 12.8 MB bf16 [N,64]
    uint2* hsb2    = (uint2*)(ws + (22u << 20));             // 12.8 MB bf16 [N,64]
    int*   pairs   = (int*)hsb2;                             // 7.04 MB transient (dead before hsb2 written)

    int nb_sc   = (e + EPB - 1) / EPB;   // 391
    int nb_rows = (n + 63) / 64;         // 1563
    int nb_agg  = (n + 15) / 16;         // 6250 (16 nodes per block)

    hipMemsetAsync(bcursor, 0, NBUCK * sizeof(int), stream);
    // fused: edge-bucket scatter (391 blocks) || layer-1 GEMM (1563 blocks)
    k_scatter_mfma1<<<nb_sc + nb_rows, 256, 0, stream>>>(srcv, dstv, bcursor, pairs, e,
                                                         (const float4*)x, W1, hsb1,
                                                         n, nb_sc);
    k_csr_bucket<<<NBUCK, 256, 0, stream>>>(pairs, bcursor, rowinfo, dinv, csr_src, n);
    // layer-1 agg (dinv[src] weights) + finalize + layer-2 GEMM fused
    k_agg1_gemm2<<<nb_agg, 256, 0, stream>>>(rowinfo, csr_src, (const uint4*)hsb1,
                                             dinv, (const float4*)b1, W2, hsb2, n);
    // layer-2 agg + head
    k_agg2_head<<<nb_agg, 256, 0, stream>>>(rowinfo, csr_src, (const uint4*)hsb2,
                                            dinv, (const float4*)b2, (const float4*)Wc,
                                            bc, (float*)d_out, n);
}